// Round 5
// baseline (137.944 us; speedup 1.0000x reference)
//
#include <hip/hip_runtime.h>
#include <math.h>

#define N_X   20000
#define N_ELL 48
#define N_K   1024
#define N_TAU 600
#define SPLIT 8                 // = N_XCD: part == bid&7 == XCD -> per-XCD tau-band
#define CHUNK (N_TAU / SPLIT)   // 75
#define ROWB  (N_ELL * 16)      // 768 B per x-row: 48 ells x 16B {p0,p0',p1,p1',p2,p2',pe,pe'}
#define KCH   4                 // k-chunks for cl kernel (1024/256)
#define PADN  96                // CHUNK padded so the 3x8-slot pipeline needs no guards

// ---------------------------------------------------------------------------
// fp16 helpers
__device__ __forceinline__ unsigned int pack_half2(float lo, float hi) {
    _Float16 l = (_Float16)lo, h = (_Float16)hi;
    unsigned short lu = __builtin_bit_cast(unsigned short, l);
    unsigned short hu = __builtin_bit_cast(unsigned short, h);
    return (unsigned int)lu | ((unsigned int)hu << 16);
}
// v_dot2_f32_f16: d = a.lo*b.lo + a.hi*b.hi + c  (f32 accumulate)
__device__ __forceinline__ float fdot2(unsigned int a, unsigned int b, float c) {
    float d;
    asm("v_dot2_f32_f16 %0, %1, %2, %3" : "=v"(d) : "v"(a), "v"(b), "v"(c));
    return d;
}

// ---------------------------------------------------------------------------
// Repack: P[x*48+e] = 16B {h2(p0[x],p0[x+1]), h2(p1..), h2(p2..), h2(pe..)}
// One dwordx4 per (x,ell) yields both interp rows for all 4 tables.
// Block 0 also zeroes out[3*N_ELL] (consumed by cl's atomicAdds).
__global__ __launch_bounds__(256) void repack_kernel(
    const float* __restrict__ p0, const float* __restrict__ p1,
    const float* __restrict__ p2, const float* __restrict__ pe,
    uint4* __restrict__ P, float* __restrict__ out)
{
    if (blockIdx.x == 0 && threadIdx.x < 3 * N_ELL) out[threadIdx.x] = 0.0f;
    const int total = N_X * N_ELL;
    for (int idx = blockIdx.x * blockDim.x + threadIdx.x; idx < total;
         idx += gridDim.x * blockDim.x) {
        int x = idx / N_ELL;
        int e = idx - x * N_ELL;
        int xn = (x < N_X - 1) ? x + 1 : x;
        int a = x * N_ELL + e, b = xn * N_ELL + e;
        uint4 v;
        v.x = pack_half2(p0[a], p0[b]);
        v.y = pack_half2(p1[a], p1[b]);
        v.z = pack_half2(p2[a], p2[b]);
        v.w = pack_half2(pe[a], pe[b]);
        P[idx] = v;
    }
}

// ---------------------------------------------------------------------------
// Main kernel: grid = N_K*SPLIT blocks of 256 threads (4 waves), lane = ell.
// SPLIT=8: part = bid&7 = XCD (round-robin dispatch), so each XCD works one
// tau-band; resident k-window ~128 (log-spaced, +-12%) -> per-XCD row-band
// ~3-4 MB -> L2-resident gathers instead of L3-latency ones.
// Gather loads predicated to 48 active lanes (lanes 48-63 were 25% wasted
// TA requests for discarded duplicates). r3's fenced A/B pipeline retained:
// 3 groups x 8 slots per wave, sched_barrier(0) pinned, zero-padded tail.
__global__ __launch_bounds__(256, 4) void tl_el_packed(
    const float* __restrict__ k, const float* __restrict__ tau,
    const float* __restrict__ tau0p,
    const float* __restrict__ S0, const float* __restrict__ S1,
    const float* __restrict__ S2, const float* __restrict__ SE,
    const float* __restrict__ bx, const uint4* __restrict__ P,
    float* __restrict__ Tlp, float* __restrict__ Elp)
{
    const int bid  = blockIdx.x;
    const int part = bid & (SPLIT - 1);        // == XCD under %8 round-robin
    const int kidx = (N_K - 1) - (bid >> 3);   // slow-first: large k dispatched early
    const int t0   = part * CHUNK;
    const int tid  = threadIdx.x;
    const int wave = tid >> 6;
    const int lane = tid & 63;
    const int ell  = (lane < N_ELL) ? lane : (N_ELL - 1);

    __shared__ unsigned int off_s[PADN];    // byte offset of row i0 in P
    __shared__ uint4        WT_s[PADN];     // {h2(s0*om,s0*w), h2(s1*om,s1*w),
                                            //  h2(s2*om,s2*w), h2(se*om,se*w)}  (x wt)
    __shared__ float        redT[4][N_ELL];
    __shared__ float        redE[4][N_ELL];

    const float kk    = k[kidx];
    const float tau0  = tau0p[0];
    const float xmin  = bx[0];
    const float xmax  = bx[N_X - 1];
    const float scale = (float)(N_X - 1) / (xmax - xmin);

    if (tid < CHUNK) {
        int t = t0 + tid;
        float tt = tau[t];
        float tp = (t > 0)         ? tau[t - 1] : tt;
        float tn = (t < N_TAU - 1) ? tau[t + 1] : tt;
        float wt = 0.5f * (tn - tp);
        float x   = kk * (tau0 - tt);
        float pos = (x - xmin) * scale;
        pos = fminf(fmaxf(pos, 0.0f), (float)(N_X - 1));
        int i0 = (int)pos;                   // pos >= 0 -> trunc == floor
        if (i0 > N_X - 2) i0 = N_X - 2;
        float w  = pos - (float)i0;
        float om = 1.0f - w;
        size_t sb = (size_t)kidx * N_TAU + t;
        float s0 = wt * S0[sb], s1 = wt * S1[sb];
        float s2 = wt * S2[sb], se = wt * SE[sb];
        uint4 w2;
        w2.x = pack_half2(s0 * om, s0 * w);
        w2.y = pack_half2(s1 * om, s1 * w);
        w2.z = pack_half2(s2 * om, s2 * w);
        w2.w = pack_half2(se * om, se * w);
        WT_s[tid]  = w2;
        off_s[tid] = (unsigned int)i0 * (unsigned int)ROWB;
    } else if (tid < PADN) {                 // zero pad: pipeline tail slots
        uint4 z4; z4.x = z4.y = z4.z = z4.w = 0u;
        WT_s[tid]  = z4;
        off_s[tid] = 0u;
    }
    __syncthreads();

    const char* Pb = (const char*)P;
    const unsigned int elloff = (unsigned int)ell * 16u;
    const bool active = (lane < N_ELL);      // lanes 48-63: no loads (25% TA cut)
    float aT0 = 0.0f, aT1 = 0.0f, aT2 = 0.0f, aE = 0.0f;

    uint4 A[8], B[8];
    #pragma unroll
    for (int m = 0; m < 8; ++m) {            // hygiene: defined bits in masked lanes
        A[m].x = A[m].y = A[m].z = A[m].w = 0u;
        B[m].x = B[m].y = B[m].z = B[m].w = 0u;
    }

#define ISSUE(BUF, G)                                                      \
    if (active) {                                                          \
        _Pragma("unroll")                                                  \
        for (int m = 0; m < 8; ++m) {                                      \
            unsigned int voff = off_s[wave + 4 * m + 32 * (G)] + elloff;   \
            BUF[m] = *(const uint4*)(Pb + voff);                           \
        }                                                                  \
    }

#define CONSUME(BUF, G)                                                    \
    _Pragma("unroll")                                                      \
    for (int m = 0; m < 8; ++m) {                                          \
        int idx = wave + 4 * m + 32 * (G);                                 \
        uint4 w2 = WT_s[idx];                                              \
        aT0 = fdot2(BUF[m].x, w2.x, aT0);                                  \
        aT1 = fdot2(BUF[m].y, w2.y, aT1);                                  \
        aT2 = fdot2(BUF[m].z, w2.z, aT2);                                  \
        aE  = fdot2(BUF[m].w, w2.w, aE);                                   \
    }

#define SB __builtin_amdgcn_sched_barrier(0)

    ISSUE(A, 0); SB;
    ISSUE(B, 1); SB;
    CONSUME(A, 0); ISSUE(A, 2); SB;
    CONSUME(B, 1); SB;
    CONSUME(A, 2);

#undef ISSUE
#undef CONSUME
#undef SB

    float accT = (aT0 + aT1) + aT2;

    if (lane < N_ELL) { redT[wave][lane] = accT; redE[wave][lane] = aE; }
    __syncthreads();
    if (tid < N_ELL) {
        float sT = (redT[0][tid] + redT[1][tid]) + (redT[2][tid] + redT[3][tid]);
        float sE = (redE[0][tid] + redE[1][tid]) + (redE[2][tid] + redE[3][tid]);
        Tlp[((size_t)part * N_ELL + tid) * N_K + kidx] = sT;
        Elp[((size_t)part * N_ELL + tid) * N_K + kidx] = sE;
    }
}

// ---------------------------------------------------------------------------
// Fallback (fp32 path) if ws can't hold the packed table + partials.
__global__ __launch_bounds__(256) void tl_el_kernel(
    const float* __restrict__ k, const float* __restrict__ tau,
    const float* __restrict__ tau0p,
    const float* __restrict__ S0, const float* __restrict__ S1,
    const float* __restrict__ S2, const float* __restrict__ SE,
    const float* __restrict__ bx,
    const float* __restrict__ p0, const float* __restrict__ p1,
    const float* __restrict__ p2, const float* __restrict__ pe,
    float* __restrict__ Tl, float* __restrict__ El)
{
    const int kidx = blockIdx.x;
    const int tid  = threadIdx.x;
    const int wave = tid >> 6;
    const int lane = tid & 63;
    const int ell  = (lane < N_ELL) ? lane : (N_ELL - 1);

    const float kk    = k[kidx];
    const float tau0  = tau0p[0];
    const float xmin  = bx[0];
    const float xmax  = bx[N_X - 1];
    const float scale = (float)(N_X - 1) / (xmax - xmin);

    const float* Srow0 = S0 + (size_t)kidx * N_TAU;
    const float* Srow1 = S1 + (size_t)kidx * N_TAU;
    const float* Srow2 = S2 + (size_t)kidx * N_TAU;
    const float* SrowE = SE + (size_t)kidx * N_TAU;

    float accT = 0.0f, accE = 0.0f;

    for (int t = wave; t < N_TAU; t += 4) {
        float tt    = tau[t];
        float tprev = (t > 0)         ? tau[t - 1] : tt;
        float tnext = (t < N_TAU - 1) ? tau[t + 1] : tt;
        float wt    = 0.5f * (tnext - tprev);

        float x   = kk * (tau0 - tt);
        float pos = (x - xmin) * scale;
        pos = fminf(fmaxf(pos, 0.0f), (float)(N_X - 1));
        int i0 = (int)floorf(pos);
        if (i0 > N_X - 2) i0 = N_X - 2;
        float w = pos - (float)i0;

        int base = i0 * N_ELL + ell;
        float y00 = p0[base], y01 = p0[base + N_ELL];
        float y10 = p1[base], y11 = p1[base + N_ELL];
        float y20 = p2[base], y21 = p2[base + N_ELL];
        float ye0 = pe[base], ye1 = pe[base + N_ELL];

        float a0 = fmaf(w, y01 - y00, y00);
        float a1 = fmaf(w, y11 - y10, y10);
        float a2 = fmaf(w, y21 - y20, y20);
        float ae = fmaf(w, ye1 - ye0, ye0);

        float s0 = Srow0[t], s1 = Srow1[t], s2 = Srow2[t], se = SrowE[t];

        float srcT = s0 * a0 + s1 * a1 + s2 * a2;
        accT = fmaf(wt, srcT, accT);
        accE = fmaf(wt, se * ae, accE);
    }

    __shared__ float redT[4][N_ELL];
    __shared__ float redE[4][N_ELL];
    if (lane < N_ELL) { redT[wave][lane] = accT; redE[wave][lane] = accE; }
    __syncthreads();
    if (tid < N_ELL) {
        float sT = (redT[0][tid] + redT[1][tid]) + (redT[2][tid] + redT[3][tid]);
        float sE = (redE[0][tid] + redE[1][tid]) + (redE[2][tid] + redE[3][tid]);
        Tl[tid * N_K + kidx] = sT;
        El[tid * N_K + kidx] = sE;
    }
}

// ---------------------------------------------------------------------------
// Kernel 2: grid (N_ELL, KCH); one k-point per thread; partial trapezoid over
// this chunk's k, atomicAdd into pre-zeroed out[3][N_ELL].
__global__ __launch_bounds__(256) void cl_kernel2(
    const float* __restrict__ k,
    const float* __restrict__ Asp, const float* __restrict__ nsp,
    const float* __restrict__ Tlp, const float* __restrict__ Elp,
    int nparts, float* __restrict__ out)
{
    const int ell   = blockIdx.x;
    const int chunk = blockIdx.y;
    const int tid   = threadIdx.x;
    const int i     = chunk * 256 + tid;        // N_K = KCH*256 exactly
    const float A_s = Asp[0];
    const float n_s = nsp[0];
    const float two_pi2 = 2.0f * (float)M_PI * (float)M_PI;

    float kv    = k[i];
    float kprev = (i > 0)       ? k[i - 1] : kv;
    float knext = (i < N_K - 1) ? k[i + 1] : kv;
    float dkw   = 0.5f * (knext - kprev);
    float Pw    = A_s * powf(kv / 0.05f, n_s - 1.0f) * two_pi2 / kv;
    float ww    = dkw * Pw;

    float tl = 0.0f, el = 0.0f;
    for (int p = 0; p < nparts; ++p) {
        tl += Tlp[((size_t)p * N_ELL + ell) * N_K + i];
        el += Elp[((size_t)p * N_ELL + ell) * N_K + i];
    }
    float aTT = ww * tl * tl;
    float aEE = ww * el * el;
    float aTE = ww * tl * el;

    for (int off = 32; off > 0; off >>= 1) {
        aTT += __shfl_down(aTT, off, 64);
        aEE += __shfl_down(aEE, off, 64);
        aTE += __shfl_down(aTE, off, 64);
    }
    __shared__ float red[3][4];
    const int wave = tid >> 6, lane = tid & 63;
    if (lane == 0) { red[0][wave] = aTT; red[1][wave] = aEE; red[2][wave] = aTE; }
    __syncthreads();
    if (tid == 0) {
        const float c = 2.0f / (float)M_PI;
        atomicAdd(&out[0 * N_ELL + ell],
                  c * ((red[0][0] + red[0][1]) + (red[0][2] + red[0][3])));
        atomicAdd(&out[1 * N_ELL + ell],
                  c * ((red[1][0] + red[1][1]) + (red[1][2] + red[1][3])));
        atomicAdd(&out[2 * N_ELL + ell],
                  c * ((red[2][0] + red[2][1]) + (red[2][2] + red[2][3])));
    }
}

extern "C" void kernel_launch(void* const* d_in, const int* in_sizes, int n_in,
                              void* d_out, int out_size, void* d_ws, size_t ws_size,
                              hipStream_t stream) {
    const float* k    = (const float*)d_in[0];
    const float* tau  = (const float*)d_in[1];
    const float* tau0 = (const float*)d_in[2];
    const float* S0   = (const float*)d_in[3];
    const float* S1   = (const float*)d_in[4];
    const float* S2   = (const float*)d_in[5];
    const float* SE   = (const float*)d_in[6];
    const float* bx   = (const float*)d_in[7];
    const float* p0   = (const float*)d_in[8];
    const float* p1   = (const float*)d_in[9];
    const float* p2   = (const float*)d_in[10];
    const float* pe   = (const float*)d_in[11];
    const float* A_s  = (const float*)d_in[12];
    const float* n_s  = (const float*)d_in[13];
    float* out = (float*)d_out;

    const size_t P_bytes    = (size_t)N_X * N_ELL * sizeof(uint4);              // 15.36 MB
    const size_t part_bytes = (size_t)SPLIT * N_ELL * N_K * sizeof(float);      // 1.57 MB

    if (ws_size >= P_bytes + 2 * part_bytes) {
        uint4* P   = (uint4*)d_ws;
        float* Tlp = (float*)((char*)d_ws + P_bytes);
        float* Elp = (float*)((char*)d_ws + P_bytes + part_bytes);

        repack_kernel<<<(N_X * N_ELL + 255) / 256, 256, 0, stream>>>(
            p0, p1, p2, pe, P, out);
        tl_el_packed<<<N_K * SPLIT, 256, 0, stream>>>(k, tau, tau0, S0, S1, S2, SE, bx,
                                                      P, Tlp, Elp);
        cl_kernel2<<<dim3(N_ELL, KCH), 256, 0, stream>>>(k, A_s, n_s, Tlp, Elp,
                                                         SPLIT, out);
    } else {
        float* Tl = (float*)d_ws;
        float* El = Tl + (size_t)N_ELL * N_K;
        hipMemsetAsync(out, 0, 3 * N_ELL * sizeof(float), stream);
        tl_el_kernel<<<N_K, 256, 0, stream>>>(k, tau, tau0, S0, S1, S2, SE, bx,
                                              p0, p1, p2, pe, Tl, El);
        cl_kernel2<<<dim3(N_ELL, KCH), 256, 0, stream>>>(k, A_s, n_s, Tl, El, 1, out);
    }
}

// Round 6
// 135.111 us; speedup vs baseline: 1.0210x; 1.0210x over previous
//
#include <hip/hip_runtime.h>
#include <math.h>

#define N_X    20000
#define N_ELL  48
#define N_K    1024
#define N_TAU  600
#define SPLIT  4
#define CHUNK  (N_TAU / SPLIT)  // 150
#define ROWB   (N_ELL * 16)     // 768 B per x-row: 48 ells x 16B {p0,p0',p1,p1',p2,p2',pe,pe'}
#define KCH    4                // k-chunks for cl kernel (1024/256)
#define PADN   160              // CHUNK padded so the 5-group pipeline needs no guards
#define KSMALL 532              // kidx < KSMALL: band = k*4627 rows <= 56 -> LDS-staged path
#define MAXR   60               // staged row-band capacity (60*768 = 46 KB LDS)

// ---------------------------------------------------------------------------
// fp16 helpers
__device__ __forceinline__ unsigned int pack_half2(float lo, float hi) {
    _Float16 l = (_Float16)lo, h = (_Float16)hi;
    unsigned short lu = __builtin_bit_cast(unsigned short, l);
    unsigned short hu = __builtin_bit_cast(unsigned short, h);
    return (unsigned int)lu | ((unsigned int)hu << 16);
}
// v_dot2_f32_f16: d = a.lo*b.lo + a.hi*b.hi + c  (f32 accumulate)
__device__ __forceinline__ float fdot2(unsigned int a, unsigned int b, float c) {
    float d;
    asm("v_dot2_f32_f16 %0, %1, %2, %3" : "=v"(d) : "v"(a), "v"(b), "v"(c));
    return d;
}

// ---------------------------------------------------------------------------
// Repack: P[x*48+e] = 16B {h2(p0[x],p0[x+1]), h2(p1..), h2(p2..), h2(pe..)}
// One dwordx4 per (x,ell) yields both interp rows for all 4 tables.
// Block 0 also zeroes out[3*N_ELL] (consumed by cl's atomicAdds).
__global__ __launch_bounds__(256) void repack_kernel(
    const float* __restrict__ p0, const float* __restrict__ p1,
    const float* __restrict__ p2, const float* __restrict__ pe,
    uint4* __restrict__ P, float* __restrict__ out)
{
    if (blockIdx.x == 0 && threadIdx.x < 3 * N_ELL) out[threadIdx.x] = 0.0f;
    const int total = N_X * N_ELL;
    for (int idx = blockIdx.x * blockDim.x + threadIdx.x; idx < total;
         idx += gridDim.x * blockDim.x) {
        int x = idx / N_ELL;
        int e = idx - x * N_ELL;
        int xn = (x < N_X - 1) ? x + 1 : x;
        int a = x * N_ELL + e, b = xn * N_ELL + e;
        uint4 v;
        v.x = pack_half2(p0[a], p0[b]);
        v.y = pack_half2(p1[a], p1[b]);
        v.z = pack_half2(p2[a], p2[b]);
        v.w = pack_half2(pe[a], pe[b]);
        P[idx] = v;
    }
}

// ---------------------------------------------------------------------------
// Shared prologue: per-tau metadata (row index + packed weights) into LDS.
__device__ __forceinline__ void build_meta(
    int tid, int t0, int kidx, float kk, float tau0, float xmin, float scale,
    const float* __restrict__ tau,
    const float* __restrict__ S0, const float* __restrict__ S1,
    const float* __restrict__ S2, const float* __restrict__ SE,
    int* row_s, uint4* WT_s)
{
    if (tid < CHUNK) {
        int t = t0 + tid;
        float tt = tau[t];
        float tp = (t > 0)         ? tau[t - 1] : tt;
        float tn = (t < N_TAU - 1) ? tau[t + 1] : tt;
        float wt = 0.5f * (tn - tp);
        float x   = kk * (tau0 - tt);
        float pos = (x - xmin) * scale;
        pos = fminf(fmaxf(pos, 0.0f), (float)(N_X - 1));
        int i0 = (int)pos;                   // pos >= 0 -> trunc == floor
        if (i0 > N_X - 2) i0 = N_X - 2;
        float w  = pos - (float)i0;
        float om = 1.0f - w;
        size_t sb = (size_t)kidx * N_TAU + t;
        float s0 = wt * S0[sb], s1 = wt * S1[sb];
        float s2 = wt * S2[sb], se = wt * SE[sb];
        uint4 w2;
        w2.x = pack_half2(s0 * om, s0 * w);
        w2.y = pack_half2(s1 * om, s1 * w);
        w2.z = pack_half2(s2 * om, s2 * w);
        w2.w = pack_half2(se * om, se * w);
        WT_s[tid] = w2;
        row_s[tid] = i0;
    } else if (tid < PADN) {                 // zero pad: pipeline tail slots
        uint4 z4; z4.x = z4.y = z4.z = z4.w = 0u;
        WT_s[tid] = z4;
        row_s[tid] = 0;
    }
}

// ---------------------------------------------------------------------------
// Gather kernel (large k, kidx >= KSMALL): r3's fenced 2x8 A/B pipeline.
// grid = (N_K-KSMALL)*SPLIT blocks of 256 threads, lane = ell.
__global__ __launch_bounds__(256, 4) void tl_el_gather(
    const float* __restrict__ k, const float* __restrict__ tau,
    const float* __restrict__ tau0p,
    const float* __restrict__ S0, const float* __restrict__ S1,
    const float* __restrict__ S2, const float* __restrict__ SE,
    const float* __restrict__ bx, const uint4* __restrict__ P,
    float* __restrict__ Tlp, float* __restrict__ Elp)
{
    const int bid  = blockIdx.x;
    const int part = bid & (SPLIT - 1);
    const int kidx = (N_K - 1) - (bid >> 2);   // slow-first: largest k dispatched early
    const int t0   = part * CHUNK;
    const int tid  = threadIdx.x;
    const int wave = tid >> 6;
    const int lane = tid & 63;
    const int ell  = (lane < N_ELL) ? lane : (N_ELL - 1);

    __shared__ int   row_s[PADN];
    __shared__ uint4 WT_s[PADN];
    __shared__ float redT[4][N_ELL];
    __shared__ float redE[4][N_ELL];

    const float kk    = k[kidx];
    const float tau0  = tau0p[0];
    const float xmin  = bx[0];
    const float xmax  = bx[N_X - 1];
    const float scale = (float)(N_X - 1) / (xmax - xmin);

    build_meta(tid, t0, kidx, kk, tau0, xmin, scale, tau, S0, S1, S2, SE,
               row_s, WT_s);
    __syncthreads();

    const char* Pb = (const char*)P;
    const unsigned int elloff = (unsigned int)ell * 16u;
    float aT0 = 0.0f, aT1 = 0.0f, aT2 = 0.0f, aE = 0.0f;

    uint4 A[8], B[8];

#define ISSUE(BUF, G)                                                      \
    _Pragma("unroll")                                                      \
    for (int m = 0; m < 8; ++m) {                                          \
        unsigned int voff =                                                \
            (unsigned int)row_s[wave + 4 * m + 32 * (G)] * (unsigned int)ROWB \
            + elloff;                                                      \
        BUF[m] = *(const uint4*)(Pb + voff);                               \
    }

#define CONSUME(BUF, G)                                                    \
    _Pragma("unroll")                                                      \
    for (int m = 0; m < 8; ++m) {                                          \
        int idx = wave + 4 * m + 32 * (G);                                 \
        uint4 w2 = WT_s[idx];                                              \
        aT0 = fdot2(BUF[m].x, w2.x, aT0);                                  \
        aT1 = fdot2(BUF[m].y, w2.y, aT1);                                  \
        aT2 = fdot2(BUF[m].z, w2.z, aT2);                                  \
        aE  = fdot2(BUF[m].w, w2.w, aE);                                   \
    }

#define SB __builtin_amdgcn_sched_barrier(0)

    ISSUE(A, 0); SB;
    ISSUE(B, 1); SB;
    CONSUME(A, 0); ISSUE(A, 2); SB;
    CONSUME(B, 1); ISSUE(B, 3); SB;
    CONSUME(A, 2); ISSUE(A, 4); SB;
    CONSUME(B, 3); SB;
    CONSUME(A, 4);

#undef ISSUE
#undef CONSUME
#undef SB

    float accT = (aT0 + aT1) + aT2;

    if (lane < N_ELL) { redT[wave][lane] = accT; redE[wave][lane] = aE; }
    __syncthreads();
    if (tid < N_ELL) {
        float sT = (redT[0][tid] + redT[1][tid]) + (redT[2][tid] + redT[3][tid]);
        float sE = (redE[0][tid] + redE[1][tid]) + (redE[2][tid] + redE[3][tid]);
        Tlp[((size_t)part * N_ELL + tid) * N_K + kidx] = sT;
        Elp[((size_t)part * N_ELL + tid) * N_K + kidx] = sE;
    }
}

// ---------------------------------------------------------------------------
// Staged kernel (small k, kidx < KSMALL): the 150-tau chunk touches a band of
// <= 56 consecutive x-rows (band = k*4627 rows, k <= k[531] = 0.0119).
// Stage the band into LDS once (dense coalesced dwordx4), then the inner loop
// is 1 ds_read_b128 + 4 fdot2 per tau — no multi-line gathers at all.
// grid = KSMALL*SPLIT blocks of 256 threads, lane = ell.
__global__ __launch_bounds__(256) void tl_el_staged(
    const float* __restrict__ k, const float* __restrict__ tau,
    const float* __restrict__ tau0p,
    const float* __restrict__ S0, const float* __restrict__ S1,
    const float* __restrict__ S2, const float* __restrict__ SE,
    const float* __restrict__ bx, const uint4* __restrict__ P,
    float* __restrict__ Tlp, float* __restrict__ Elp)
{
    const int bid  = blockIdx.x;
    const int part = bid & (SPLIT - 1);
    const int kidx = (KSMALL - 1) - (bid >> 2);  // biggest staged bands first
    const int t0   = part * CHUNK;
    const int tid  = threadIdx.x;
    const int wave = tid >> 6;
    const int lane = tid & 63;
    const int ell  = (lane < N_ELL) ? lane : (N_ELL - 1);

    __shared__ int   row_s[PADN];
    __shared__ uint4 WT_s[PADN];
    __shared__ uint4 band[MAXR * N_ELL];    // 60*48*16 = 46080 B
    __shared__ float redT[4][N_ELL];
    __shared__ float redE[4][N_ELL];

    const float kk    = k[kidx];
    const float tau0  = tau0p[0];
    const float xmin  = bx[0];
    const float xmax  = bx[N_X - 1];
    const float scale = (float)(N_X - 1) / (xmax - xmin);

    build_meta(tid, t0, kidx, kk, tau0, xmin, scale, tau, S0, S1, S2, SE,
               row_s, WT_s);
    __syncthreads();

    // x = k*(tau0 - tau) is monotone decreasing in tau -> endpoints bound band.
    const int imax = row_s[0];
    const int imin = row_s[CHUNK - 1];
    const int nrows = imax - imin + 1;
    float aT0 = 0.0f, aT1 = 0.0f, aT2 = 0.0f, aE = 0.0f;

    if (nrows <= MAXR) {
        // stage band rows [imin, imax] (each row already holds {x, x+1} pairs)
        const uint4* src = P + (size_t)imin * N_ELL;
        const int nelem = nrows * N_ELL;     // <= 2880
        #pragma unroll 4
        for (int j = tid; j < nelem; j += 256) band[j] = src[j];
        __syncthreads();

        for (int idx = wave; idx < CHUNK; idx += 4) {
            uint4 pr = band[(row_s[idx] - imin) * N_ELL + ell];
            uint4 w2 = WT_s[idx];
            aT0 = fdot2(pr.x, w2.x, aT0);
            aT1 = fdot2(pr.y, w2.y, aT1);
            aT2 = fdot2(pr.z, w2.z, aT2);
            aE  = fdot2(pr.w, w2.w, aE);
        }
    } else {
        // safety fallback (statically unreachable for kidx < KSMALL)
        for (int idx = wave; idx < CHUNK; idx += 4) {
            uint4 pr = P[(size_t)row_s[idx] * N_ELL + ell];
            uint4 w2 = WT_s[idx];
            aT0 = fdot2(pr.x, w2.x, aT0);
            aT1 = fdot2(pr.y, w2.y, aT1);
            aT2 = fdot2(pr.z, w2.z, aT2);
            aE  = fdot2(pr.w, w2.w, aE);
        }
    }

    float accT = (aT0 + aT1) + aT2;

    if (lane < N_ELL) { redT[wave][lane] = accT; redE[wave][lane] = aE; }
    __syncthreads();
    if (tid < N_ELL) {
        float sT = (redT[0][tid] + redT[1][tid]) + (redT[2][tid] + redT[3][tid]);
        float sE = (redE[0][tid] + redE[1][tid]) + (redE[2][tid] + redE[3][tid]);
        Tlp[((size_t)part * N_ELL + tid) * N_K + kidx] = sT;
        Elp[((size_t)part * N_ELL + tid) * N_K + kidx] = sE;
    }
}

// ---------------------------------------------------------------------------
// Fallback (fp32 path) if ws can't hold the packed table + partials.
__global__ __launch_bounds__(256) void tl_el_kernel(
    const float* __restrict__ k, const float* __restrict__ tau,
    const float* __restrict__ tau0p,
    const float* __restrict__ S0, const float* __restrict__ S1,
    const float* __restrict__ S2, const float* __restrict__ SE,
    const float* __restrict__ bx,
    const float* __restrict__ p0, const float* __restrict__ p1,
    const float* __restrict__ p2, const float* __restrict__ pe,
    float* __restrict__ Tl, float* __restrict__ El)
{
    const int kidx = blockIdx.x;
    const int tid  = threadIdx.x;
    const int wave = tid >> 6;
    const int lane = tid & 63;
    const int ell  = (lane < N_ELL) ? lane : (N_ELL - 1);

    const float kk    = k[kidx];
    const float tau0  = tau0p[0];
    const float xmin  = bx[0];
    const float xmax  = bx[N_X - 1];
    const float scale = (float)(N_X - 1) / (xmax - xmin);

    const float* Srow0 = S0 + (size_t)kidx * N_TAU;
    const float* Srow1 = S1 + (size_t)kidx * N_TAU;
    const float* Srow2 = S2 + (size_t)kidx * N_TAU;
    const float* SrowE = SE + (size_t)kidx * N_TAU;

    float accT = 0.0f, accE = 0.0f;

    for (int t = wave; t < N_TAU; t += 4) {
        float tt    = tau[t];
        float tprev = (t > 0)         ? tau[t - 1] : tt;
        float tnext = (t < N_TAU - 1) ? tau[t + 1] : tt;
        float wt    = 0.5f * (tnext - tprev);

        float x   = kk * (tau0 - tt);
        float pos = (x - xmin) * scale;
        pos = fminf(fmaxf(pos, 0.0f), (float)(N_X - 1));
        int i0 = (int)floorf(pos);
        if (i0 > N_X - 2) i0 = N_X - 2;
        float w = pos - (float)i0;

        int base = i0 * N_ELL + ell;
        float y00 = p0[base], y01 = p0[base + N_ELL];
        float y10 = p1[base], y11 = p1[base + N_ELL];
        float y20 = p2[base], y21 = p2[base + N_ELL];
        float ye0 = pe[base], ye1 = pe[base + N_ELL];

        float a0 = fmaf(w, y01 - y00, y00);
        float a1 = fmaf(w, y11 - y10, y10);
        float a2 = fmaf(w, y21 - y20, y20);
        float ae = fmaf(w, ye1 - ye0, ye0);

        float s0 = Srow0[t], s1 = Srow1[t], s2 = Srow2[t], se = SrowE[t];

        float srcT = s0 * a0 + s1 * a1 + s2 * a2;
        accT = fmaf(wt, srcT, accT);
        accE = fmaf(wt, se * ae, accE);
    }

    __shared__ float redT[4][N_ELL];
    __shared__ float redE[4][N_ELL];
    if (lane < N_ELL) { redT[wave][lane] = accT; redE[wave][lane] = accE; }
    __syncthreads();
    if (tid < N_ELL) {
        float sT = (redT[0][tid] + redT[1][tid]) + (redT[2][tid] + redT[3][tid]);
        float sE = (redE[0][tid] + redE[1][tid]) + (redE[2][tid] + redE[3][tid]);
        Tl[tid * N_K + kidx] = sT;
        El[tid * N_K + kidx] = sE;
    }
}

// ---------------------------------------------------------------------------
// Kernel 2: grid (N_ELL, KCH); one k-point per thread; partial trapezoid over
// this chunk's k, atomicAdd into pre-zeroed out[3][N_ELL].
__global__ __launch_bounds__(256) void cl_kernel2(
    const float* __restrict__ k,
    const float* __restrict__ Asp, const float* __restrict__ nsp,
    const float* __restrict__ Tlp, const float* __restrict__ Elp,
    int nparts, float* __restrict__ out)
{
    const int ell   = blockIdx.x;
    const int chunk = blockIdx.y;
    const int tid   = threadIdx.x;
    const int i     = chunk * 256 + tid;        // N_K = KCH*256 exactly
    const float A_s = Asp[0];
    const float n_s = nsp[0];
    const float two_pi2 = 2.0f * (float)M_PI * (float)M_PI;

    float kv    = k[i];
    float kprev = (i > 0)       ? k[i - 1] : kv;
    float knext = (i < N_K - 1) ? k[i + 1] : kv;
    float dkw   = 0.5f * (knext - kprev);
    float Pw    = A_s * powf(kv / 0.05f, n_s - 1.0f) * two_pi2 / kv;
    float ww    = dkw * Pw;

    float tl = 0.0f, el = 0.0f;
    for (int p = 0; p < nparts; ++p) {
        tl += Tlp[((size_t)p * N_ELL + ell) * N_K + i];
        el += Elp[((size_t)p * N_ELL + ell) * N_K + i];
    }
    float aTT = ww * tl * tl;
    float aEE = ww * el * el;
    float aTE = ww * tl * el;

    for (int off = 32; off > 0; off >>= 1) {
        aTT += __shfl_down(aTT, off, 64);
        aEE += __shfl_down(aEE, off, 64);
        aTE += __shfl_down(aTE, off, 64);
    }
    __shared__ float red[3][4];
    const int wave = tid >> 6, lane = tid & 63;
    if (lane == 0) { red[0][wave] = aTT; red[1][wave] = aEE; red[2][wave] = aTE; }
    __syncthreads();
    if (tid == 0) {
        const float c = 2.0f / (float)M_PI;
        atomicAdd(&out[0 * N_ELL + ell],
                  c * ((red[0][0] + red[0][1]) + (red[0][2] + red[0][3])));
        atomicAdd(&out[1 * N_ELL + ell],
                  c * ((red[1][0] + red[1][1]) + (red[1][2] + red[1][3])));
        atomicAdd(&out[2 * N_ELL + ell],
                  c * ((red[2][0] + red[2][1]) + (red[2][2] + red[2][3])));
    }
}

extern "C" void kernel_launch(void* const* d_in, const int* in_sizes, int n_in,
                              void* d_out, int out_size, void* d_ws, size_t ws_size,
                              hipStream_t stream) {
    const float* k    = (const float*)d_in[0];
    const float* tau  = (const float*)d_in[1];
    const float* tau0 = (const float*)d_in[2];
    const float* S0   = (const float*)d_in[3];
    const float* S1   = (const float*)d_in[4];
    const float* S2   = (const float*)d_in[5];
    const float* SE   = (const float*)d_in[6];
    const float* bx   = (const float*)d_in[7];
    const float* p0   = (const float*)d_in[8];
    const float* p1   = (const float*)d_in[9];
    const float* p2   = (const float*)d_in[10];
    const float* pe   = (const float*)d_in[11];
    const float* A_s  = (const float*)d_in[12];
    const float* n_s  = (const float*)d_in[13];
    float* out = (float*)d_out;

    const size_t P_bytes    = (size_t)N_X * N_ELL * sizeof(uint4);              // 15.36 MB
    const size_t part_bytes = (size_t)SPLIT * N_ELL * N_K * sizeof(float);      // 786 KB

    if (ws_size >= P_bytes + 2 * part_bytes) {
        uint4* P   = (uint4*)d_ws;
        float* Tlp = (float*)((char*)d_ws + P_bytes);
        float* Elp = (float*)((char*)d_ws + P_bytes + part_bytes);

        repack_kernel<<<(N_X * N_ELL + 255) / 256, 256, 0, stream>>>(
            p0, p1, p2, pe, P, out);
        tl_el_gather<<<(N_K - KSMALL) * SPLIT, 256, 0, stream>>>(
            k, tau, tau0, S0, S1, S2, SE, bx, P, Tlp, Elp);
        tl_el_staged<<<KSMALL * SPLIT, 256, 0, stream>>>(
            k, tau, tau0, S0, S1, S2, SE, bx, P, Tlp, Elp);
        cl_kernel2<<<dim3(N_ELL, KCH), 256, 0, stream>>>(k, A_s, n_s, Tlp, Elp,
                                                         SPLIT, out);
    } else {
        float* Tl = (float*)d_ws;
        float* El = Tl + (size_t)N_ELL * N_K;
        hipMemsetAsync(out, 0, 3 * N_ELL * sizeof(float), stream);
        tl_el_kernel<<<N_K, 256, 0, stream>>>(k, tau, tau0, S0, S1, S2, SE, bx,
                                              p0, p1, p2, pe, Tl, El);
        cl_kernel2<<<dim3(N_ELL, KCH), 256, 0, stream>>>(k, A_s, n_s, Tl, El, 1, out);
    }
}

// Round 7
// 128.361 us; speedup vs baseline: 1.0747x; 1.0526x over previous
//
#include <hip/hip_runtime.h>
#include <math.h>

#define N_X    20000
#define N_ELL  48
#define N_K    1024
#define N_TAU  600
#define SPLIT  4
#define CHUNK  (N_TAU / SPLIT)  // 150
#define ROWB   (N_ELL * 16)     // 768 B per x-row: 48 ells x 16B {p0,p0',p1,p1',p2,p2',pe,pe'}
#define KCH    4                // k-chunks for cl kernel (1024/256)
#define PADN   160              // CHUNK padded so the 5-group pipeline needs no guards
#define KSMALL 434              // kidx < KSMALL: chunk band = k*4650+2 rows <= 25 -> LDS path
#define MAXR   26               // staged row-band capacity (26*768 = 19.5 KB LDS)

// ---------------------------------------------------------------------------
// fp16 helpers
__device__ __forceinline__ unsigned int pack_half2(float lo, float hi) {
    _Float16 l = (_Float16)lo, h = (_Float16)hi;
    unsigned short lu = __builtin_bit_cast(unsigned short, l);
    unsigned short hu = __builtin_bit_cast(unsigned short, h);
    return (unsigned int)lu | ((unsigned int)hu << 16);
}
// v_dot2_f32_f16: d = a.lo*b.lo + a.hi*b.hi + c  (f32 accumulate)
__device__ __forceinline__ float fdot2(unsigned int a, unsigned int b, float c) {
    float d;
    asm("v_dot2_f32_f16 %0, %1, %2, %3" : "=v"(d) : "v"(a), "v"(b), "v"(c));
    return d;
}

// ---------------------------------------------------------------------------
// Repack: P[x*48+e] = 16B {h2(p0[x],p0[x+1]), h2(p1..), h2(p2..), h2(pe..)}
// One dwordx4 per (x,ell) yields both interp rows for all 4 tables.
// Block 0 also zeroes out[3*N_ELL] (consumed by cl's atomicAdds).
__global__ __launch_bounds__(256) void repack_kernel(
    const float* __restrict__ p0, const float* __restrict__ p1,
    const float* __restrict__ p2, const float* __restrict__ pe,
    uint4* __restrict__ P, float* __restrict__ out)
{
    if (blockIdx.x == 0 && threadIdx.x < 3 * N_ELL) out[threadIdx.x] = 0.0f;
    const int total = N_X * N_ELL;
    for (int idx = blockIdx.x * blockDim.x + threadIdx.x; idx < total;
         idx += gridDim.x * blockDim.x) {
        int x = idx / N_ELL;
        int e = idx - x * N_ELL;
        int xn = (x < N_X - 1) ? x + 1 : x;
        int a = x * N_ELL + e, b = xn * N_ELL + e;
        uint4 v;
        v.x = pack_half2(p0[a], p0[b]);
        v.y = pack_half2(p1[a], p1[b]);
        v.z = pack_half2(p2[a], p2[b]);
        v.w = pack_half2(pe[a], pe[b]);
        P[idx] = v;
    }
}

// ---------------------------------------------------------------------------
// Shared prologue: per-tau metadata (row index + packed weights) into LDS.
__device__ __forceinline__ void build_meta(
    int tid, int t0, int kidx, float kk, float tau0, float xmin, float scale,
    const float* __restrict__ tau,
    const float* __restrict__ S0, const float* __restrict__ S1,
    const float* __restrict__ S2, const float* __restrict__ SE,
    int* row_s, uint4* WT_s)
{
    if (tid < CHUNK) {
        int t = t0 + tid;
        float tt = tau[t];
        float tp = (t > 0)         ? tau[t - 1] : tt;
        float tn = (t < N_TAU - 1) ? tau[t + 1] : tt;
        float wt = 0.5f * (tn - tp);
        float x   = kk * (tau0 - tt);
        float pos = (x - xmin) * scale;
        pos = fminf(fmaxf(pos, 0.0f), (float)(N_X - 1));
        int i0 = (int)pos;                   // pos >= 0 -> trunc == floor
        if (i0 > N_X - 2) i0 = N_X - 2;
        float w  = pos - (float)i0;
        float om = 1.0f - w;
        size_t sb = (size_t)kidx * N_TAU + t;
        float s0 = wt * S0[sb], s1 = wt * S1[sb];
        float s2 = wt * S2[sb], se = wt * SE[sb];
        uint4 w2;
        w2.x = pack_half2(s0 * om, s0 * w);
        w2.y = pack_half2(s1 * om, s1 * w);
        w2.z = pack_half2(s2 * om, s2 * w);
        w2.w = pack_half2(se * om, se * w);
        WT_s[tid] = w2;
        row_s[tid] = i0;
    } else if (tid < PADN) {                 // zero pad: pipeline tail slots
        uint4 z4; z4.x = z4.y = z4.z = z4.w = 0u;
        WT_s[tid] = z4;
        row_s[tid] = 0;
    }
}

// ---------------------------------------------------------------------------
// Hybrid kernel: grid = N_K*SPLIT blocks of 256 threads (4 waves), lane = ell.
// Block-uniform branch on kidx:
//  - kidx >= KSMALL (large k): r3's fenced 2x8 A/B gather pipeline (proven
//    129.9 us config) — untouched.
//  - kidx <  KSMALL (small k): the 150-tau chunk touches <= 26 consecutive
//    x-rows; stage the band into LDS once (dense coalesced dwordx4), inner
//    loop = 1 ds_read_b128 + 4 fdot2 per tau. Removes the 12-line gather
//    lookups these blocks would otherwise push through the TCP/L2.
// Accumulation order identical in both paths (tau ascending per thread) ->
// bit-identical results vs r3.
__global__ __launch_bounds__(256, 4) void tl_el_hybrid(
    const float* __restrict__ k, const float* __restrict__ tau,
    const float* __restrict__ tau0p,
    const float* __restrict__ S0, const float* __restrict__ S1,
    const float* __restrict__ S2, const float* __restrict__ SE,
    const float* __restrict__ bx, const uint4* __restrict__ P,
    float* __restrict__ Tlp, float* __restrict__ Elp)
{
    const int bid  = blockIdx.x;
    const int part = bid & (SPLIT - 1);
    const int kidx = (N_K - 1) - (bid >> 2);   // slow-first: largest k dispatched early
    const int t0   = part * CHUNK;
    const int tid  = threadIdx.x;
    const int wave = tid >> 6;
    const int lane = tid & 63;
    const int ell  = (lane < N_ELL) ? lane : (N_ELL - 1);

    __shared__ int   row_s[PADN];
    __shared__ uint4 WT_s[PADN];
    __shared__ uint4 band[MAXR * N_ELL];    // 26*48*16 = 19968 B (staged path only)
    __shared__ float redT[4][N_ELL];
    __shared__ float redE[4][N_ELL];

    const float kk    = k[kidx];
    const float tau0  = tau0p[0];
    const float xmin  = bx[0];
    const float xmax  = bx[N_X - 1];
    const float scale = (float)(N_X - 1) / (xmax - xmin);

    build_meta(tid, t0, kidx, kk, tau0, xmin, scale, tau, S0, S1, S2, SE,
               row_s, WT_s);
    __syncthreads();

    float aT0 = 0.0f, aT1 = 0.0f, aT2 = 0.0f, aE = 0.0f;

    if (kidx >= KSMALL) {
        // ---------------- gather path (r3 pipeline, unchanged) ----------------
        const char* Pb = (const char*)P;
        const unsigned int elloff = (unsigned int)ell * 16u;
        uint4 A[8], B[8];

#define ISSUE(BUF, G)                                                      \
    _Pragma("unroll")                                                      \
    for (int m = 0; m < 8; ++m) {                                          \
        unsigned int voff =                                                \
            (unsigned int)row_s[wave + 4 * m + 32 * (G)] * (unsigned int)ROWB \
            + elloff;                                                      \
        BUF[m] = *(const uint4*)(Pb + voff);                               \
    }

#define CONSUME(BUF, G)                                                    \
    _Pragma("unroll")                                                      \
    for (int m = 0; m < 8; ++m) {                                          \
        int idx = wave + 4 * m + 32 * (G);                                 \
        uint4 w2 = WT_s[idx];                                              \
        aT0 = fdot2(BUF[m].x, w2.x, aT0);                                  \
        aT1 = fdot2(BUF[m].y, w2.y, aT1);                                  \
        aT2 = fdot2(BUF[m].z, w2.z, aT2);                                  \
        aE  = fdot2(BUF[m].w, w2.w, aE);                                   \
    }

#define SB __builtin_amdgcn_sched_barrier(0)

        ISSUE(A, 0); SB;
        ISSUE(B, 1); SB;
        CONSUME(A, 0); ISSUE(A, 2); SB;
        CONSUME(B, 1); ISSUE(B, 3); SB;
        CONSUME(A, 2); ISSUE(A, 4); SB;
        CONSUME(B, 3); SB;
        CONSUME(A, 4);

#undef ISSUE
#undef CONSUME
#undef SB
    } else {
        // ---------------- staged path (small k) ----------------
        // x = k*(tau0 - tau) monotone decreasing in tau -> endpoints bound band.
        const int imax = row_s[0];
        const int imin = row_s[CHUNK - 1];
        const int nrows = imax - imin + 1;

        if (nrows <= MAXR) {
            const uint4* src = P + (size_t)imin * N_ELL;
            const int nelem = nrows * N_ELL;     // <= 1248
            for (int j = tid; j < nelem; j += 256) band[j] = src[j];
            __syncthreads();

            for (int idx = wave; idx < CHUNK; idx += 4) {
                uint4 pr = band[(row_s[idx] - imin) * N_ELL + ell];
                uint4 w2 = WT_s[idx];
                aT0 = fdot2(pr.x, w2.x, aT0);
                aT1 = fdot2(pr.y, w2.y, aT1);
                aT2 = fdot2(pr.z, w2.z, aT2);
                aE  = fdot2(pr.w, w2.w, aE);
            }
        } else {
            // safety fallback (statically unreachable for kidx < KSMALL)
            for (int idx = wave; idx < CHUNK; idx += 4) {
                uint4 pr = P[(size_t)row_s[idx] * N_ELL + ell];
                uint4 w2 = WT_s[idx];
                aT0 = fdot2(pr.x, w2.x, aT0);
                aT1 = fdot2(pr.y, w2.y, aT1);
                aT2 = fdot2(pr.z, w2.z, aT2);
                aE  = fdot2(pr.w, w2.w, aE);
            }
        }
    }

    float accT = (aT0 + aT1) + aT2;

    if (lane < N_ELL) { redT[wave][lane] = accT; redE[wave][lane] = aE; }
    __syncthreads();
    if (tid < N_ELL) {
        float sT = (redT[0][tid] + redT[1][tid]) + (redT[2][tid] + redT[3][tid]);
        float sE = (redE[0][tid] + redE[1][tid]) + (redE[2][tid] + redE[3][tid]);
        Tlp[((size_t)part * N_ELL + tid) * N_K + kidx] = sT;
        Elp[((size_t)part * N_ELL + tid) * N_K + kidx] = sE;
    }
}

// ---------------------------------------------------------------------------
// Fallback (fp32 path) if ws can't hold the packed table + partials.
__global__ __launch_bounds__(256) void tl_el_kernel(
    const float* __restrict__ k, const float* __restrict__ tau,
    const float* __restrict__ tau0p,
    const float* __restrict__ S0, const float* __restrict__ S1,
    const float* __restrict__ S2, const float* __restrict__ SE,
    const float* __restrict__ bx,
    const float* __restrict__ p0, const float* __restrict__ p1,
    const float* __restrict__ p2, const float* __restrict__ pe,
    float* __restrict__ Tl, float* __restrict__ El)
{
    const int kidx = blockIdx.x;
    const int tid  = threadIdx.x;
    const int wave = tid >> 6;
    const int lane = tid & 63;
    const int ell  = (lane < N_ELL) ? lane : (N_ELL - 1);

    const float kk    = k[kidx];
    const float tau0  = tau0p[0];
    const float xmin  = bx[0];
    const float xmax  = bx[N_X - 1];
    const float scale = (float)(N_X - 1) / (xmax - xmin);

    const float* Srow0 = S0 + (size_t)kidx * N_TAU;
    const float* Srow1 = S1 + (size_t)kidx * N_TAU;
    const float* Srow2 = S2 + (size_t)kidx * N_TAU;
    const float* SrowE = SE + (size_t)kidx * N_TAU;

    float accT = 0.0f, accE = 0.0f;

    for (int t = wave; t < N_TAU; t += 4) {
        float tt    = tau[t];
        float tprev = (t > 0)         ? tau[t - 1] : tt;
        float tnext = (t < N_TAU - 1) ? tau[t + 1] : tt;
        float wt    = 0.5f * (tnext - tprev);

        float x   = kk * (tau0 - tt);
        float pos = (x - xmin) * scale;
        pos = fminf(fmaxf(pos, 0.0f), (float)(N_X - 1));
        int i0 = (int)floorf(pos);
        if (i0 > N_X - 2) i0 = N_X - 2;
        float w = pos - (float)i0;

        int base = i0 * N_ELL + ell;
        float y00 = p0[base], y01 = p0[base + N_ELL];
        float y10 = p1[base], y11 = p1[base + N_ELL];
        float y20 = p2[base], y21 = p2[base + N_ELL];
        float ye0 = pe[base], ye1 = pe[base + N_ELL];

        float a0 = fmaf(w, y01 - y00, y00);
        float a1 = fmaf(w, y11 - y10, y10);
        float a2 = fmaf(w, y21 - y20, y20);
        float ae = fmaf(w, ye1 - ye0, ye0);

        float s0 = Srow0[t], s1 = Srow1[t], s2 = Srow2[t], se = SrowE[t];

        float srcT = s0 * a0 + s1 * a1 + s2 * a2;
        accT = fmaf(wt, srcT, accT);
        accE = fmaf(wt, se * ae, accE);
    }

    __shared__ float redT[4][N_ELL];
    __shared__ float redE[4][N_ELL];
    if (lane < N_ELL) { redT[wave][lane] = accT; redE[wave][lane] = accE; }
    __syncthreads();
    if (tid < N_ELL) {
        float sT = (redT[0][tid] + redT[1][tid]) + (redT[2][tid] + redT[3][tid]);
        float sE = (redE[0][tid] + redE[1][tid]) + (redE[2][tid] + redE[3][tid]);
        Tl[tid * N_K + kidx] = sT;
        El[tid * N_K + kidx] = sE;
    }
}

// ---------------------------------------------------------------------------
// Kernel 2: grid (N_ELL, KCH); one k-point per thread; partial trapezoid over
// this chunk's k, atomicAdd into pre-zeroed out[3][N_ELL].
__global__ __launch_bounds__(256) void cl_kernel2(
    const float* __restrict__ k,
    const float* __restrict__ Asp, const float* __restrict__ nsp,
    const float* __restrict__ Tlp, const float* __restrict__ Elp,
    int nparts, float* __restrict__ out)
{
    const int ell   = blockIdx.x;
    const int chunk = blockIdx.y;
    const int tid   = threadIdx.x;
    const int i     = chunk * 256 + tid;        // N_K = KCH*256 exactly
    const float A_s = Asp[0];
    const float n_s = nsp[0];
    const float two_pi2 = 2.0f * (float)M_PI * (float)M_PI;

    float kv    = k[i];
    float kprev = (i > 0)       ? k[i - 1] : kv;
    float knext = (i < N_K - 1) ? k[i + 1] : kv;
    float dkw   = 0.5f * (knext - kprev);
    float Pw    = A_s * powf(kv / 0.05f, n_s - 1.0f) * two_pi2 / kv;
    float ww    = dkw * Pw;

    float tl = 0.0f, el = 0.0f;
    for (int p = 0; p < nparts; ++p) {
        tl += Tlp[((size_t)p * N_ELL + ell) * N_K + i];
        el += Elp[((size_t)p * N_ELL + ell) * N_K + i];
    }
    float aTT = ww * tl * tl;
    float aEE = ww * el * el;
    float aTE = ww * tl * el;

    for (int off = 32; off > 0; off >>= 1) {
        aTT += __shfl_down(aTT, off, 64);
        aEE += __shfl_down(aEE, off, 64);
        aTE += __shfl_down(aTE, off, 64);
    }
    __shared__ float red[3][4];
    const int wave = tid >> 6, lane = tid & 63;
    if (lane == 0) { red[0][wave] = aTT; red[1][wave] = aEE; red[2][wave] = aTE; }
    __syncthreads();
    if (tid == 0) {
        const float c = 2.0f / (float)M_PI;
        atomicAdd(&out[0 * N_ELL + ell],
                  c * ((red[0][0] + red[0][1]) + (red[0][2] + red[0][3])));
        atomicAdd(&out[1 * N_ELL + ell],
                  c * ((red[1][0] + red[1][1]) + (red[1][2] + red[1][3])));
        atomicAdd(&out[2 * N_ELL + ell],
                  c * ((red[2][0] + red[2][1]) + (red[2][2] + red[2][3])));
    }
}

extern "C" void kernel_launch(void* const* d_in, const int* in_sizes, int n_in,
                              void* d_out, int out_size, void* d_ws, size_t ws_size,
                              hipStream_t stream) {
    const float* k    = (const float*)d_in[0];
    const float* tau  = (const float*)d_in[1];
    const float* tau0 = (const float*)d_in[2];
    const float* S0   = (const float*)d_in[3];
    const float* S1   = (const float*)d_in[4];
    const float* S2   = (const float*)d_in[5];
    const float* SE   = (const float*)d_in[6];
    const float* bx   = (const float*)d_in[7];
    const float* p0   = (const float*)d_in[8];
    const float* p1   = (const float*)d_in[9];
    const float* p2   = (const float*)d_in[10];
    const float* pe   = (const float*)d_in[11];
    const float* A_s  = (const float*)d_in[12];
    const float* n_s  = (const float*)d_in[13];
    float* out = (float*)d_out;

    const size_t P_bytes    = (size_t)N_X * N_ELL * sizeof(uint4);              // 15.36 MB
    const size_t part_bytes = (size_t)SPLIT * N_ELL * N_K * sizeof(float);      // 786 KB

    if (ws_size >= P_bytes + 2 * part_bytes) {
        uint4* P   = (uint4*)d_ws;
        float* Tlp = (float*)((char*)d_ws + P_bytes);
        float* Elp = (float*)((char*)d_ws + P_bytes + part_bytes);

        repack_kernel<<<(N_X * N_ELL + 255) / 256, 256, 0, stream>>>(
            p0, p1, p2, pe, P, out);
        tl_el_hybrid<<<N_K * SPLIT, 256, 0, stream>>>(k, tau, tau0, S0, S1, S2, SE,
                                                      bx, P, Tlp, Elp);
        cl_kernel2<<<dim3(N_ELL, KCH), 256, 0, stream>>>(k, A_s, n_s, Tlp, Elp,
                                                         SPLIT, out);
    } else {
        float* Tl = (float*)d_ws;
        float* El = Tl + (size_t)N_ELL * N_K;
        hipMemsetAsync(out, 0, 3 * N_ELL * sizeof(float), stream);
        tl_el_kernel<<<N_K, 256, 0, stream>>>(k, tau, tau0, S0, S1, S2, SE, bx,
                                              p0, p1, p2, pe, Tl, El);
        cl_kernel2<<<dim3(N_ELL, KCH), 256, 0, stream>>>(k, A_s, n_s, Tl, El, 1, out);
    }
}